// Round 7
// baseline (500.079 us; speedup 1.0000x reference)
//
#include <hip/hip_runtime.h>
#include <hip/hip_bf16.h>

#define L_ 2048
#define S_ 2048
#define NB 4
#define E_ 1024
#define H_ 16
#define D_ 64
#define LDT 72   // padded LDS row (bf16 units) for GEMM kernels
#define NCH (S_ / 64)

typedef __attribute__((ext_vector_type(8))) short bf16x8;
typedef __attribute__((ext_vector_type(4))) float f32x4;

__device__ __forceinline__ short f2bf(float f) {
  union { float f; unsigned u; } v; v.f = f;
  unsigned r = v.u + 0x7FFFu + ((v.u >> 16) & 1u);
  return (short)(r >> 16);
}
__device__ __forceinline__ float bf2f(short s) {
  union { unsigned u; float f; } v; v.u = ((unsigned)(unsigned short)s) << 16;
  return v.f;
}
// packed f32x2 -> bf16x2 (RNE, same rounding as f2bf)
__device__ __forceinline__ unsigned cvt_pk_bf16(float lo, float hi) {
  unsigned r;
  asm("v_cvt_pk_bf16_f32 %0, %1, %2" : "=v"(r) : "v"(lo), "v"(hi));
  return r;
}

// LDS-visibility-only barrier: does NOT drain vmcnt (global prefetches survive).
#define LGKM_BARRIER() do {                                   \
    asm volatile("s_waitcnt lgkmcnt(0)" ::: "memory");        \
    __builtin_amdgcn_sched_barrier(0);                        \
    __builtin_amdgcn_s_barrier();                             \
    __builtin_amdgcn_sched_barrier(0);                        \
  } while (0)

// ---------------- kernel 1: weight fp32 -> bf16 ----------------
__global__ void k_convert(const float* __restrict__ wi, const float* __restrict__ wo,
                          short* __restrict__ wqkv, short* __restrict__ wout) {
  const int n1 = 3 * E_ * E_ / 4;
  const int n2 = E_ * E_ / 4;
  const int stride = gridDim.x * blockDim.x;
  for (int i = blockIdx.x * blockDim.x + threadIdx.x; i < n1 + n2; i += stride) {
    const float4* s; short* d; int j;
    if (i < n1) { s = (const float4*)wi; d = wqkv; j = i; }
    else        { s = (const float4*)wo; d = wout; j = i - n1; }
    float4 v = s[j];
    uint2 o; o.x = cvt_pk_bf16(v.x, v.y); o.y = cvt_pk_bf16(v.z, v.w);
    *(uint2*)&d[(size_t)j * 4] = o;
  }
}

// ---------------- kernel 2: fused QKV projection GEMM ----------------
// q pre-scaled by (1/8)*log2(e) so softmax uses exp2 directly
__global__ __launch_bounds__(256) void k_qkv(
    const float* __restrict__ qin, const float* __restrict__ kin, const float* __restrict__ vin,
    const short* __restrict__ wbf, const float* __restrict__ bias,
    short* __restrict__ qh, short* __restrict__ kh, short* __restrict__ vh) {
  __shared__ short As[128 * LDT];
  __shared__ short Bs[128 * LDT];
  const int bm = blockIdx.x;
  const int fbase = blockIdx.y * 128;
  const int mat = fbase >> 10;
  const float* __restrict__ A = (mat == 0) ? qin : (mat == 1) ? kin : vin;
  short* __restrict__ dst = (mat == 0) ? qh : (mat == 1) ? kh : vh;
  const float scale = (mat == 0) ? 0.125f * 1.44269504088896f : 1.0f;
  const int tid = threadIdx.x;
  const int lane = tid & 63, wid = tid >> 6;
  const int wr = wid >> 1, wc = wid & 1;
  const int lr = lane & 15, lk = lane >> 4;
  f32x4 acc[4][4] = {};

  for (int kb = 0; kb < E_; kb += 64) {
#pragma unroll
    for (int i = 0; i < 8; ++i) {
      int f4 = i * 256 + tid;
      int row = f4 >> 4, k4 = f4 & 15;
      float4 v = *(const float4*)&A[(size_t)(bm * 128 + row) * E_ + kb + k4 * 4];
      uint2 o; o.x = cvt_pk_bf16(v.x, v.y); o.y = cvt_pk_bf16(v.z, v.w);
      *(uint2*)&As[row * LDT + k4 * 4] = o;
    }
#pragma unroll
    for (int i = 0; i < 4; ++i) {
      int e8 = i * 256 + tid;
      int row = e8 >> 3, k8 = e8 & 7;
      int4 v = *(const int4*)&wbf[(size_t)(fbase + row) * E_ + kb + k8 * 8];
      *(int4*)&Bs[row * LDT + k8 * 8] = v;
    }
    __syncthreads();
#pragma unroll
    for (int kk = 0; kk < 2; ++kk) {
      bf16x8 a[4], b[4];
#pragma unroll
      for (int fi = 0; fi < 4; ++fi)
        a[fi] = *(const bf16x8*)&As[(wr * 64 + fi * 16 + lr) * LDT + kk * 32 + lk * 8];
#pragma unroll
      for (int ci = 0; ci < 4; ++ci)
        b[ci] = *(const bf16x8*)&Bs[(wc * 64 + ci * 16 + lr) * LDT + kk * 32 + lk * 8];
#pragma unroll
      for (int fi = 0; fi < 4; ++fi)
#pragma unroll
        for (int ci = 0; ci < 4; ++ci)
          acc[fi][ci] = __builtin_amdgcn_mfma_f32_16x16x32_bf16(a[fi], b[ci], acc[fi][ci], 0, 0, 0);
    }
    __syncthreads();
  }
#pragma unroll
  for (int ci = 0; ci < 4; ++ci) {
    const int fg = fbase + wc * 64 + ci * 16 + lr;
    const float b = bias[fg];
    const int col = fg & 1023;
    const int h = col >> 6, d = col & 63;
#pragma unroll
    for (int fi = 0; fi < 4; ++fi)
#pragma unroll
      for (int j = 0; j < 4; ++j) {
        int m = bm * 128 + wr * 64 + fi * 16 + lk * 4 + j;
        int t = m >> 2, n = m & 3;
        float vv = (acc[fi][ci][j] + b) * scale;
        dst[(((size_t)(n * H_ + h) * L_ + t) << 6) + d] = f2bf(vv);
      }
  }
}

// ---------------- kernel 2b: V -> blocked V^T per head ----------------
// vh[nh][t][d] -> vtb[nh][s/32][d][32]  (each 32x64 tile contiguous: 4KB)
__global__ __launch_bounds__(256) void k_vtrans(const short* __restrict__ vh,
                                                short* __restrict__ vt) {
  __shared__ short t[64][LDT];
  const int nh = blockIdx.y;
  const int tb = blockIdx.x;
  const int tid = threadIdx.x;
  const short* __restrict__ src = vh + ((size_t)nh * L_ + tb * 64) * D_;
  short* __restrict__ dst = vt + (size_t)nh * S_ * D_;
#pragma unroll
  for (int i = 0; i < 2; ++i) {
    int v = i * 256 + tid;
    int r = v >> 3, c8 = v & 7;
    *(bf16x8*)&t[r][c8 * 8] = *(const bf16x8*)&src[(size_t)r * D_ + c8 * 8];
  }
  __syncthreads();
#pragma unroll
  for (int i = 0; i < 2; ++i) {
    int v = i * 256 + tid;
    int d = v >> 3, t8 = v & 7;
    bf16x8 o;
#pragma unroll
    for (int e = 0; e < 8; ++e) o[e] = t[t8 * 8 + e][d];
    int sb = tb * 2 + (t8 >> 2);
    *(bf16x8*)&dst[(size_t)sb * (D_ * 32) + d * 32 + (t8 & 3) * 8] = o;
  }
}

// ---------------- kernel 3: softmax denominators (reciprocal) ----------------
// reload-after-use K pipeline (no barriers here; adds load cover per st-iter)
__global__ __launch_bounds__(256) void k_stats(
    const short* __restrict__ qh, const short* __restrict__ kh, float* __restrict__ rl) {
  const int nh = blockIdx.y;
  const int qt = blockIdx.x;
  const short* __restrict__ Q = qh + (size_t)nh * L_ * D_;
  const short* __restrict__ K = kh + (size_t)nh * S_ * D_;
  const int tid = threadIdx.x;
  const int lane = tid & 63, wid = tid >> 6;
  const int lr = lane & 15, lk = lane >> 4;
  const int rbase = qt * 128 + wid * 32;
  bf16x8 a[2][2];
#pragma unroll
  for (int ri = 0; ri < 2; ++ri)
#pragma unroll
    for (int kk = 0; kk < 2; ++kk)
      a[ri][kk] = *(const bf16x8*)&Q[(size_t)(rbase + ri * 16 + lr) * D_ + kk * 32 + lk * 8];
  bf16x8 kst[4][2];
#pragma unroll
  for (int ci = 0; ci < 4; ++ci) {
    kst[ci][0] = *(const bf16x8*)&K[(size_t)(ci * 16 + lr) * D_ + lk * 8];
    kst[ci][1] = *(const bf16x8*)&K[(size_t)(ci * 16 + lr) * D_ + 32 + lk * 8];
  }
  float ssum[2][4] = {};
  for (int st = 0; st < S_; st += 64) {
    const int stn = (st + 64 < S_) ? st + 64 : st;
    f32x4 acc[2][4] = {};
#pragma unroll
    for (int ci = 0; ci < 4; ++ci) {
#pragma unroll
      for (int ri = 0; ri < 2; ++ri) {
        acc[ri][ci] = __builtin_amdgcn_mfma_f32_16x16x32_bf16(a[ri][0], kst[ci][0], acc[ri][ci], 0, 0, 0);
        acc[ri][ci] = __builtin_amdgcn_mfma_f32_16x16x32_bf16(a[ri][1], kst[ci][1], acc[ri][ci], 0, 0, 0);
      }
      kst[ci][0] = *(const bf16x8*)&K[(size_t)(stn + ci * 16 + lr) * D_ + lk * 8];
      kst[ci][1] = *(const bf16x8*)&K[(size_t)(stn + ci * 16 + lr) * D_ + 32 + lk * 8];
    }
#pragma unroll
    for (int ri = 0; ri < 2; ++ri)
#pragma unroll
      for (int j = 0; j < 4; ++j) {
        float s = __builtin_amdgcn_exp2f(acc[ri][0][j]) + __builtin_amdgcn_exp2f(acc[ri][1][j]) +
                  __builtin_amdgcn_exp2f(acc[ri][2][j]) + __builtin_amdgcn_exp2f(acc[ri][3][j]);
        s += __shfl_xor(s, 1);
        s += __shfl_xor(s, 2);
        s += __shfl_xor(s, 4);
        s += __shfl_xor(s, 8);
        ssum[ri][j] += s;
      }
  }
  if (lr == 0) {
#pragma unroll
    for (int ri = 0; ri < 2; ++ri)
#pragma unroll
      for (int j = 0; j < 4; ++j)
        rl[(size_t)nh * L_ + rbase + ri * 16 + lk * 4 + j] = 1.0f / ssum[ri][j];
  }
}

// ---------------- kernel 4: attention ----------------
// block = (32-row q-tile, n); 1024 threads = 16 waves, one head each.
// 64-S chunks; psl double-buffered 2x64KB, XOR-swizzled; one lgkm-only
// barrier per chunk. K/V register fragments reloaded for chunk t+1
// immediately after their last use in chunk t (loads stay in flight
// across the barrier -> latency hidden under pack/PV/mean phases).
__global__ __launch_bounds__(1024) void k_attn(
    const short* __restrict__ qh, const short* __restrict__ kh, const short* __restrict__ vt,
    const float* __restrict__ rl, float* __restrict__ attnw, short* __restrict__ ctx) {
  extern __shared__ char psl[];  // [2][16 heads][32 rows][128B], byte ^= (row&7)<<4
  const int n = blockIdx.y, qt = blockIdx.x;
  const int tid = threadIdx.x;
  const int h = tid >> 6, lane = tid & 63;
  const int lr = lane & 15, lk = lane >> 4;
  const int rbase = qt * 32;
  const size_t nh = (size_t)(n * H_ + h);
  const short* __restrict__ K = kh + nh * S_ * D_;
  const short* __restrict__ VT = vt + nh * S_ * D_;
  char* const slab0 = psl + h * 4096;

  bf16x8 qf[2][2];
  float rls[2];
  {
    const short* Q = qh + nh * L_ * D_;
#pragma unroll
    for (int li = 0; li < 2; ++li) {
#pragma unroll
      for (int kk = 0; kk < 2; ++kk)
        qf[li][kk] = *(const bf16x8*)&Q[(size_t)(rbase + li * 16 + lr) * D_ + kk * 32 + lk * 8];
      rls[li] = rl[nh * L_ + rbase + li * 16 + lr];
    }
  }
  f32x4 cacc[2][4] = {};
  // mean-phase geometry: 1024 threads cover 32 rows x 64 cols (2 cols each)
  const int mrow = tid >> 5, mc2 = (tid & 31) * 2;
  float* awp = attnw + ((size_t)n * L_ + rbase + mrow) * S_ + mc2;
  const int moff = mrow * 128 + ((mc2 * 2) ^ ((mrow & 7) << 4));  // byte offset

  // ---- preload chunk 0 K and V fragments
  bf16x8 kb[4][2], vb[4][2];
#pragma unroll
  for (int u = 0; u < 4; ++u) {
    kb[u][0] = *(const bf16x8*)&K[(size_t)(u * 16 + lr) * D_ + lk * 8];
    kb[u][1] = *(const bf16x8*)&K[(size_t)(u * 16 + lr) * D_ + 32 + lk * 8];
  }
#pragma unroll
  for (int b = 0; b < 2; ++b) {
    const size_t sb = (size_t)b * (D_ * 32);
#pragma unroll
    for (int ci = 0; ci < 4; ++ci)
      vb[ci][b] = *(const bf16x8*)&VT[sb + (ci * 16 + lr) * 32 + lk * 8];
  }

  for (int ch = 0; ch < NCH; ++ch) {
    const int st = ch * 64;
    const int stn = (ch + 1 < NCH) ? st + 64 : st;  // clamped (last iter redundant)
    char* const sl = slab0 + (ch & 1) * 65536;
    // ---- QK^T per 16-s subtile; reload kb[u] for next chunk right after use
#pragma unroll
    for (int u = 0; u < 4; ++u) {
      f32x4 sc0 = {}, sc1 = {};
      sc0 = __builtin_amdgcn_mfma_f32_16x16x32_bf16(kb[u][0], qf[0][0], sc0, 0, 0, 0);
      sc0 = __builtin_amdgcn_mfma_f32_16x16x32_bf16(kb[u][1], qf[0][1], sc0, 0, 0, 0);
      sc1 = __builtin_amdgcn_mfma_f32_16x16x32_bf16(kb[u][0], qf[1][0], sc1, 0, 0, 0);
      sc1 = __builtin_amdgcn_mfma_f32_16x16x32_bf16(kb[u][1], qf[1][1], sc1, 0, 0, 0);
      kb[u][0] = *(const bf16x8*)&K[(size_t)(stn + u * 16 + lr) * D_ + lk * 8];
      kb[u][1] = *(const bf16x8*)&K[(size_t)(stn + u * 16 + lr) * D_ + 32 + lk * 8];
      {
        uint2 pk;
        pk.x = cvt_pk_bf16(__builtin_amdgcn_exp2f(sc0[0]) * rls[0],
                           __builtin_amdgcn_exp2f(sc0[1]) * rls[0]);
        pk.y = cvt_pk_bf16(__builtin_amdgcn_exp2f(sc0[2]) * rls[0],
                           __builtin_amdgcn_exp2f(sc0[3]) * rls[0]);
        const int row = lr;
        *(uint2*)(sl + row * 128 + ((u * 32 + lk * 8) ^ ((row & 7) << 4))) = pk;
      }
      {
        uint2 pk;
        pk.x = cvt_pk_bf16(__builtin_amdgcn_exp2f(sc1[0]) * rls[1],
                           __builtin_amdgcn_exp2f(sc1[1]) * rls[1]);
        pk.y = cvt_pk_bf16(__builtin_amdgcn_exp2f(sc1[2]) * rls[1],
                           __builtin_amdgcn_exp2f(sc1[3]) * rls[1]);
        const int row = 16 + lr;
        *(uint2*)(sl + row * 128 + ((u * 32 + lk * 8) ^ ((row & 7) << 4))) = pk;
      }
    }
    // ---- PV per 32-s half; reload vb[.][b] for next chunk right after use
#pragma unroll
    for (int b = 0; b < 2; ++b) {
#pragma unroll
      for (int li = 0; li < 2; ++li) {
        const int row = li * 16 + lr;
        bf16x8 pa = *(const bf16x8*)(sl + row * 128 + ((b * 64 + lk * 16) ^ ((row & 7) << 4)));
#pragma unroll
        for (int ci = 0; ci < 4; ++ci)
          cacc[li][ci] = __builtin_amdgcn_mfma_f32_16x16x32_bf16(pa, vb[ci][b], cacc[li][ci], 0, 0, 0);
      }
      const size_t sbn = (size_t)((stn >> 5) + b) * (D_ * 32);
#pragma unroll
      for (int ci = 0; ci < 4; ++ci)
        vb[ci][b] = *(const bf16x8*)&VT[sbn + (ci * 16 + lr) * 32 + lk * 8];
    }
    // ---- head-mean of PREVIOUS chunk (other buffer; overlaps this chunk)
    if (ch > 0) {
      char* const ms = psl + (((ch & 1) ^ 1)) * 65536;
      float s0 = 0.f, s1 = 0.f;
#pragma unroll
      for (int hh = 0; hh < 16; ++hh) {
        short2 m = *(const short2*)(ms + hh * 4096 + moff);
        s0 += bf2f(m.x); s1 += bf2f(m.y);
      }
      *(float2*)&awp[st - 64] = make_float2(s0 * 0.0625f, s1 * 0.0625f);
    }
    LGKM_BARRIER();  // publish chunk ch; mean reads of ch-1 complete
  }
  // ---- final chunk's mean (chunk NCH-1 lives in buffer 1)
  {
    char* const ms = psl + 65536;
    float s0 = 0.f, s1 = 0.f;
#pragma unroll
    for (int hh = 0; hh < 16; ++hh) {
      short2 m = *(const short2*)(ms + hh * 4096 + moff);
      s0 += bf2f(m.x); s1 += bf2f(m.y);
    }
    *(float2*)&awp[S_ - 64] = make_float2(s0 * 0.0625f, s1 * 0.0625f);
  }
  // ---- ctx write: [l][n][h*64+d] bf16
#pragma unroll
  for (int li = 0; li < 2; ++li)
#pragma unroll
    for (int ci = 0; ci < 4; ++ci)
#pragma unroll
      for (int j = 0; j < 4; ++j) {
        int row = rbase + li * 16 + lk * 4 + j;
        int d = ci * 16 + lr;
        ctx[((size_t)row * NB + n) * E_ + h * 64 + d] = f2bf(cacc[li][ci][j]);
      }
}

// ---------------- kernel 5: output projection ----------------
__global__ __launch_bounds__(256) void k_out(
    const short* __restrict__ ctxb, const short* __restrict__ wbf,
    const float* __restrict__ bias, float* __restrict__ out) {
  __shared__ short As[128 * LDT];
  __shared__ short Bs[128 * LDT];
  const int bm = blockIdx.x, bn = blockIdx.y;
  const int tid = threadIdx.x;
  const int lane = tid & 63, wid = tid >> 6;
  const int wr = wid >> 1, wc = wid & 1;
  const int lr = lane & 15, lk = lane >> 4;
  f32x4 acc[4][4] = {};
  for (int kb = 0; kb < E_; kb += 64) {
#pragma unroll
    for (int i = 0; i < 4; ++i) {
      int e8 = i * 256 + tid;
      int row = e8 >> 3, k8 = e8 & 7;
      int4 va = *(const int4*)&ctxb[(size_t)(bm * 128 + row) * E_ + kb + k8 * 8];
      *(int4*)&As[row * LDT + k8 * 8] = va;
      int4 vb = *(const int4*)&wbf[(size_t)(bn * 128 + row) * E_ + kb + k8 * 8];
      *(int4*)&Bs[row * LDT + k8 * 8] = vb;
    }
    __syncthreads();
#pragma unroll
    for (int kk = 0; kk < 2; ++kk) {
      bf16x8 a[4], b[4];
#pragma unroll
      for (int fi = 0; fi < 4; ++fi)
        a[fi] = *(const bf16x8*)&As[(wr * 64 + fi * 16 + lr) * LDT + kk * 32 + lk * 8];
#pragma unroll
      for (int ci = 0; ci < 4; ++ci)
        b[ci] = *(const bf16x8*)&Bs[(wc * 64 + ci * 16 + lr) * LDT + kk * 32 + lk * 8];
#pragma unroll
      for (int fi = 0; fi < 4; ++fi)
#pragma unroll
        for (int ci = 0; ci < 4; ++ci)
          acc[fi][ci] = __builtin_amdgcn_mfma_f32_16x16x32_bf16(a[fi], b[ci], acc[fi][ci], 0, 0, 0);
    }
    __syncthreads();
  }
#pragma unroll
  for (int ci = 0; ci < 4; ++ci) {
    int col = bn * 128 + wc * 64 + ci * 16 + lr;
    float b = bias[col];
#pragma unroll
    for (int fi = 0; fi < 4; ++fi)
#pragma unroll
      for (int j = 0; j < 4; ++j) {
        int m = bm * 128 + wr * 64 + fi * 16 + lk * 4 + j;
        out[(size_t)m * E_ + col] = acc[fi][ci][j] + b;
      }
  }
}

extern "C" void kernel_launch(void* const* d_in, const int* in_sizes, int n_in,
                              void* d_out, int out_size, void* d_ws, size_t ws_size,
                              hipStream_t stream) {
  const float* qin = (const float*)d_in[0];
  const float* kin = (const float*)d_in[1];
  const float* vin = (const float*)d_in[2];
  const float* wi  = (const float*)d_in[3];
  const float* bi  = (const float*)d_in[4];
  const float* wo  = (const float*)d_in[5];
  const float* bo  = (const float*)d_in[6];
  float* out = (float*)d_out;                       // (L,NB,E) fp32
  float* attnw = out + (size_t)L_ * NB * E_;        // (NB,L,S) fp32

  short* wqkv = (short*)d_ws;                       // 3E*E bf16
  short* wout = wqkv + (size_t)3 * E_ * E_;         // E*E bf16
  short* qh = wout + (size_t)E_ * E_;               // NB*H*L*D bf16 each
  short* kh = qh + (size_t)NB * L_ * E_;
  short* vh = kh + (size_t)NB * L_ * E_;
  short* vt = vh + (size_t)NB * L_ * E_;            // NB*H*(S/32)*D*32 bf16
  float* rl = (float*)(vt + (size_t)NB * L_ * E_);  // NB*H*L fp32
  short* ctx = (short*)(rl + (size_t)NB * H_ * L_); // L*NB*E bf16

  k_convert<<<1024, 256, 0, stream>>>(wi, wo, wqkv, wout);
  k_qkv<<<dim3(64, 24), 256, 0, stream>>>(qin, kin, vin, wqkv, bi, qh, kh, vh);
  k_vtrans<<<dim3(32, 64), 256, 0, stream>>>(vh, vt);
  k_stats<<<dim3(16, 64), 256, 0, stream>>>(qh, kh, rl);
  k_attn<<<dim3(64, 4), 1024, 131072, stream>>>(qh, kh, vt, rl, attnw, ctx);
  k_out<<<dim3(64, 8), 256, 0, stream>>>(ctx, wout, bo, out);
}

// Round 8
// 452.993 us; speedup vs baseline: 1.1039x; 1.1039x over previous
//
#include <hip/hip_runtime.h>
#include <hip/hip_bf16.h>

#define L_ 2048
#define S_ 2048
#define NB 4
#define E_ 1024
#define H_ 16
#define D_ 64
#define LDT 72   // padded LDS row (bf16 units) for GEMM kernels
#define NCH (S_ / 64)

typedef __attribute__((ext_vector_type(8))) short bf16x8;
typedef __attribute__((ext_vector_type(4))) float f32x4;

__device__ __forceinline__ short f2bf(float f) {
  union { float f; unsigned u; } v; v.f = f;
  unsigned r = v.u + 0x7FFFu + ((v.u >> 16) & 1u);
  return (short)(r >> 16);
}
__device__ __forceinline__ float bf2f(short s) {
  union { unsigned u; float f; } v; v.u = ((unsigned)(unsigned short)s) << 16;
  return v.f;
}
// packed f32x2 -> bf16x2 (RNE, same rounding as f2bf)
__device__ __forceinline__ unsigned cvt_pk_bf16(float lo, float hi) {
  unsigned r;
  asm("v_cvt_pk_bf16_f32 %0, %1, %2" : "=v"(r) : "v"(lo), "v"(hi));
  return r;
}

// LDS-visibility-only barrier: does NOT drain vmcnt (global prefetches survive).
#define LGKM_BARRIER() do {                                   \
    asm volatile("s_waitcnt lgkmcnt(0)" ::: "memory");        \
    __builtin_amdgcn_sched_barrier(0);                        \
    __builtin_amdgcn_s_barrier();                             \
    __builtin_amdgcn_sched_barrier(0);                        \
  } while (0)

// ---------------- kernel 1: weight fp32 -> bf16 ----------------
__global__ void k_convert(const float* __restrict__ wi, const float* __restrict__ wo,
                          short* __restrict__ wqkv, short* __restrict__ wout) {
  const int n1 = 3 * E_ * E_ / 4;
  const int n2 = E_ * E_ / 4;
  const int stride = gridDim.x * blockDim.x;
  for (int i = blockIdx.x * blockDim.x + threadIdx.x; i < n1 + n2; i += stride) {
    const float4* s; short* d; int j;
    if (i < n1) { s = (const float4*)wi; d = wqkv; j = i; }
    else        { s = (const float4*)wo; d = wout; j = i - n1; }
    float4 v = s[j];
    uint2 o; o.x = cvt_pk_bf16(v.x, v.y); o.y = cvt_pk_bf16(v.z, v.w);
    *(uint2*)&d[(size_t)j * 4] = o;
  }
}

// ---------------- kernel 2: fused QKV projection GEMM ----------------
// q pre-scaled by (1/8)*log2(e) so softmax uses exp2 directly
__global__ __launch_bounds__(256) void k_qkv(
    const float* __restrict__ qin, const float* __restrict__ kin, const float* __restrict__ vin,
    const short* __restrict__ wbf, const float* __restrict__ bias,
    short* __restrict__ qh, short* __restrict__ kh, short* __restrict__ vh) {
  __shared__ short As[128 * LDT];
  __shared__ short Bs[128 * LDT];
  const int bm = blockIdx.x;
  const int fbase = blockIdx.y * 128;
  const int mat = fbase >> 10;
  const float* __restrict__ A = (mat == 0) ? qin : (mat == 1) ? kin : vin;
  short* __restrict__ dst = (mat == 0) ? qh : (mat == 1) ? kh : vh;
  const float scale = (mat == 0) ? 0.125f * 1.44269504088896f : 1.0f;
  const int tid = threadIdx.x;
  const int lane = tid & 63, wid = tid >> 6;
  const int wr = wid >> 1, wc = wid & 1;
  const int lr = lane & 15, lk = lane >> 4;
  f32x4 acc[4][4] = {};

  for (int kb = 0; kb < E_; kb += 64) {
#pragma unroll
    for (int i = 0; i < 8; ++i) {
      int f4 = i * 256 + tid;
      int row = f4 >> 4, k4 = f4 & 15;
      float4 v = *(const float4*)&A[(size_t)(bm * 128 + row) * E_ + kb + k4 * 4];
      uint2 o; o.x = cvt_pk_bf16(v.x, v.y); o.y = cvt_pk_bf16(v.z, v.w);
      *(uint2*)&As[row * LDT + k4 * 4] = o;
    }
#pragma unroll
    for (int i = 0; i < 4; ++i) {
      int e8 = i * 256 + tid;
      int row = e8 >> 3, k8 = e8 & 7;
      int4 v = *(const int4*)&wbf[(size_t)(fbase + row) * E_ + kb + k8 * 8];
      *(int4*)&Bs[row * LDT + k8 * 8] = v;
    }
    __syncthreads();
#pragma unroll
    for (int kk = 0; kk < 2; ++kk) {
      bf16x8 a[4], b[4];
#pragma unroll
      for (int fi = 0; fi < 4; ++fi)
        a[fi] = *(const bf16x8*)&As[(wr * 64 + fi * 16 + lr) * LDT + kk * 32 + lk * 8];
#pragma unroll
      for (int ci = 0; ci < 4; ++ci)
        b[ci] = *(const bf16x8*)&Bs[(wc * 64 + ci * 16 + lr) * LDT + kk * 32 + lk * 8];
#pragma unroll
      for (int fi = 0; fi < 4; ++fi)
#pragma unroll
        for (int ci = 0; ci < 4; ++ci)
          acc[fi][ci] = __builtin_amdgcn_mfma_f32_16x16x32_bf16(a[fi], b[ci], acc[fi][ci], 0, 0, 0);
    }
    __syncthreads();
  }
#pragma unroll
  for (int ci = 0; ci < 4; ++ci) {
    const int fg = fbase + wc * 64 + ci * 16 + lr;
    const float b = bias[fg];
    const int col = fg & 1023;
    const int h = col >> 6, d = col & 63;
#pragma unroll
    for (int fi = 0; fi < 4; ++fi)
#pragma unroll
      for (int j = 0; j < 4; ++j) {
        int m = bm * 128 + wr * 64 + fi * 16 + lk * 4 + j;
        int t = m >> 2, n = m & 3;
        float vv = (acc[fi][ci][j] + b) * scale;
        dst[(((size_t)(n * H_ + h) * L_ + t) << 6) + d] = f2bf(vv);
      }
  }
}

// ---------------- kernel 2b: V -> blocked V^T per head ----------------
// vh[nh][t][d] -> vtb[nh][s/32][d][32]  (each 32x64 tile contiguous: 4KB)
__global__ __launch_bounds__(256) void k_vtrans(const short* __restrict__ vh,
                                                short* __restrict__ vt) {
  __shared__ short t[64][LDT];
  const int nh = blockIdx.y;
  const int tb = blockIdx.x;
  const int tid = threadIdx.x;
  const short* __restrict__ src = vh + ((size_t)nh * L_ + tb * 64) * D_;
  short* __restrict__ dst = vt + (size_t)nh * S_ * D_;
#pragma unroll
  for (int i = 0; i < 2; ++i) {
    int v = i * 256 + tid;
    int r = v >> 3, c8 = v & 7;
    *(bf16x8*)&t[r][c8 * 8] = *(const bf16x8*)&src[(size_t)r * D_ + c8 * 8];
  }
  __syncthreads();
#pragma unroll
  for (int i = 0; i < 2; ++i) {
    int v = i * 256 + tid;
    int d = v >> 3, t8 = v & 7;
    bf16x8 o;
#pragma unroll
    for (int e = 0; e < 8; ++e) o[e] = t[t8 * 8 + e][d];
    int sb = tb * 2 + (t8 >> 2);
    *(bf16x8*)&dst[(size_t)sb * (D_ * 32) + d * 32 + (t8 & 3) * 8] = o;
  }
}

// ---------------- kernel 3: softmax denominators (reciprocal) ----------------
// reload-after-use K pipeline (no barriers here; adds load cover per st-iter)
__global__ __launch_bounds__(256) void k_stats(
    const short* __restrict__ qh, const short* __restrict__ kh, float* __restrict__ rl) {
  const int nh = blockIdx.y;
  const int qt = blockIdx.x;
  const short* __restrict__ Q = qh + (size_t)nh * L_ * D_;
  const short* __restrict__ K = kh + (size_t)nh * S_ * D_;
  const int tid = threadIdx.x;
  const int lane = tid & 63, wid = tid >> 6;
  const int lr = lane & 15, lk = lane >> 4;
  const int rbase = qt * 128 + wid * 32;
  bf16x8 a[2][2];
#pragma unroll
  for (int ri = 0; ri < 2; ++ri)
#pragma unroll
    for (int kk = 0; kk < 2; ++kk)
      a[ri][kk] = *(const bf16x8*)&Q[(size_t)(rbase + ri * 16 + lr) * D_ + kk * 32 + lk * 8];
  bf16x8 kst[4][2];
#pragma unroll
  for (int ci = 0; ci < 4; ++ci) {
    kst[ci][0] = *(const bf16x8*)&K[(size_t)(ci * 16 + lr) * D_ + lk * 8];
    kst[ci][1] = *(const bf16x8*)&K[(size_t)(ci * 16 + lr) * D_ + 32 + lk * 8];
  }
  float ssum[2][4] = {};
  for (int st = 0; st < S_; st += 64) {
    const int stn = (st + 64 < S_) ? st + 64 : st;
    f32x4 acc[2][4] = {};
#pragma unroll
    for (int ci = 0; ci < 4; ++ci) {
#pragma unroll
      for (int ri = 0; ri < 2; ++ri) {
        acc[ri][ci] = __builtin_amdgcn_mfma_f32_16x16x32_bf16(a[ri][0], kst[ci][0], acc[ri][ci], 0, 0, 0);
        acc[ri][ci] = __builtin_amdgcn_mfma_f32_16x16x32_bf16(a[ri][1], kst[ci][1], acc[ri][ci], 0, 0, 0);
      }
      kst[ci][0] = *(const bf16x8*)&K[(size_t)(stn + ci * 16 + lr) * D_ + lk * 8];
      kst[ci][1] = *(const bf16x8*)&K[(size_t)(stn + ci * 16 + lr) * D_ + 32 + lk * 8];
    }
#pragma unroll
    for (int ri = 0; ri < 2; ++ri)
#pragma unroll
      for (int j = 0; j < 4; ++j) {
        float s = __builtin_amdgcn_exp2f(acc[ri][0][j]) + __builtin_amdgcn_exp2f(acc[ri][1][j]) +
                  __builtin_amdgcn_exp2f(acc[ri][2][j]) + __builtin_amdgcn_exp2f(acc[ri][3][j]);
        s += __shfl_xor(s, 1);
        s += __shfl_xor(s, 2);
        s += __shfl_xor(s, 4);
        s += __shfl_xor(s, 8);
        ssum[ri][j] += s;
      }
  }
  if (lr == 0) {
#pragma unroll
    for (int ri = 0; ri < 2; ++ri)
#pragma unroll
      for (int j = 0; j < 4; ++j)
        rl[(size_t)nh * L_ + rbase + ri * 16 + lk * 4 + j] = 1.0f / ssum[ri][j];
  }
}

// ---------------- kernel 4: attention ----------------
// 1D grid 256, XCD-aware decode: each batch n owns exactly 2 XCDs so its
// 8 MB K/V working set fits the XCD-pair L2. 1024 threads = 16 waves (1 head
// each); 64-S chunks; psl double-buffered 2x64KB, XOR-swizzled; one lgkm-only
// barrier per chunk (mean of chunk t-1 overlaps compute of t).
__global__ __launch_bounds__(1024) void k_attn(
    const short* __restrict__ qh, const short* __restrict__ kh, const short* __restrict__ vt,
    const float* __restrict__ rl, float* __restrict__ attnw, short* __restrict__ ctx) {
  extern __shared__ char psl[];  // [2][16 heads][32 rows][128B], byte ^= (row&7)<<4
  const int bid = blockIdx.x;
  const int xcd = bid & 7;            // HW round-robins consecutive ids over XCDs
  const int n = xcd >> 1;             // batch -> XCD pair
  const int qt = (bid >> 3) | ((xcd & 1) << 5);
  const int tid = threadIdx.x;
  const int h = tid >> 6, lane = tid & 63;
  const int lr = lane & 15, lk = lane >> 4;
  const int rbase = qt * 32;
  const size_t nh = (size_t)(n * H_ + h);
  const short* __restrict__ K = kh + nh * S_ * D_;
  const short* __restrict__ VT = vt + nh * S_ * D_;
  char* const slab0 = psl + h * 4096;

  bf16x8 qf[2][2];
  float rls[2];
  {
    const short* Q = qh + nh * L_ * D_;
#pragma unroll
    for (int li = 0; li < 2; ++li) {
#pragma unroll
      for (int kk = 0; kk < 2; ++kk)
        qf[li][kk] = *(const bf16x8*)&Q[(size_t)(rbase + li * 16 + lr) * D_ + kk * 32 + lk * 8];
      rls[li] = rl[nh * L_ + rbase + li * 16 + lr];
    }
  }
  f32x4 cacc[2][4] = {};
  // mean-phase geometry: 1024 threads cover 32 rows x 64 cols (2 cols each)
  const int mrow = tid >> 5, mc2 = (tid & 31) * 2;
  float* awp = attnw + ((size_t)n * L_ + rbase + mrow) * S_ + mc2;
  const int moff = mrow * 128 + ((mc2 * 2) ^ ((mrow & 7) << 4));  // byte offset

  for (int ch = 0; ch < NCH; ++ch) {
    const int st = ch * 64;
    char* const sl = slab0 + (ch & 1) * 65536;
    // ---- loads for this chunk: K first (used first), then V
    bf16x8 kf[4][2];
#pragma unroll
    for (int u = 0; u < 4; ++u) {
      kf[u][0] = *(const bf16x8*)&K[(size_t)(st + u * 16 + lr) * D_ + lk * 8];
      kf[u][1] = *(const bf16x8*)&K[(size_t)(st + u * 16 + lr) * D_ + 32 + lk * 8];
    }
    bf16x8 vb[4][2];
#pragma unroll
    for (int b = 0; b < 2; ++b) {
      const size_t sb = (size_t)((st >> 5) + b) * (D_ * 32);
#pragma unroll
      for (int ci = 0; ci < 4; ++ci)
        vb[ci][b] = *(const bf16x8*)&VT[sb + (ci * 16 + lr) * 32 + lk * 8];
    }
    // ---- QK^T (swapped: rows=s, cols=l) per 16-s subtile; p -> swizzled LDS
#pragma unroll
    for (int u = 0; u < 4; ++u) {
#pragma unroll
      for (int li = 0; li < 2; ++li) {
        f32x4 sc = {};
        sc = __builtin_amdgcn_mfma_f32_16x16x32_bf16(kf[u][0], qf[li][0], sc, 0, 0, 0);
        sc = __builtin_amdgcn_mfma_f32_16x16x32_bf16(kf[u][1], qf[li][1], sc, 0, 0, 0);
        uint2 pk;
        pk.x = cvt_pk_bf16(__builtin_amdgcn_exp2f(sc[0]) * rls[li],
                           __builtin_amdgcn_exp2f(sc[1]) * rls[li]);
        pk.y = cvt_pk_bf16(__builtin_amdgcn_exp2f(sc[2]) * rls[li],
                           __builtin_amdgcn_exp2f(sc[3]) * rls[li]);
        const int row = li * 16 + lr;
        *(uint2*)(sl + row * 128 + ((u * 32 + lk * 8) ^ ((row & 7) << 4))) = pk;
      }
    }
    // ---- PV from own slab (wave-local RAW)
#pragma unroll
    for (int b = 0; b < 2; ++b)
#pragma unroll
      for (int li = 0; li < 2; ++li) {
        const int row = li * 16 + lr;
        bf16x8 pa = *(const bf16x8*)(sl + row * 128 + ((b * 64 + lk * 16) ^ ((row & 7) << 4)));
#pragma unroll
        for (int ci = 0; ci < 4; ++ci)
          cacc[li][ci] = __builtin_amdgcn_mfma_f32_16x16x32_bf16(pa, vb[ci][b], cacc[li][ci], 0, 0, 0);
      }
    // ---- head-mean of PREVIOUS chunk (other buffer; overlaps this chunk)
    if (ch > 0) {
      char* const ms = psl + (((ch & 1) ^ 1)) * 65536;
      float s0 = 0.f, s1 = 0.f;
#pragma unroll
      for (int hh = 0; hh < 16; ++hh) {
        short2 m = *(const short2*)(ms + hh * 4096 + moff);
        s0 += bf2f(m.x); s1 += bf2f(m.y);
      }
      *(float2*)&awp[st - 64] = make_float2(s0 * 0.0625f, s1 * 0.0625f);
    }
    LGKM_BARRIER();  // publish chunk ch; mean reads of ch-1 complete
  }
  // ---- final chunk's mean (chunk NCH-1 lives in buffer 1)
  {
    char* const ms = psl + 65536;
    float s0 = 0.f, s1 = 0.f;
#pragma unroll
    for (int hh = 0; hh < 16; ++hh) {
      short2 m = *(const short2*)(ms + hh * 4096 + moff);
      s0 += bf2f(m.x); s1 += bf2f(m.y);
    }
    *(float2*)&awp[S_ - 64] = make_float2(s0 * 0.0625f, s1 * 0.0625f);
  }
  // ---- ctx write: [l][n][h*64+d] bf16
#pragma unroll
  for (int li = 0; li < 2; ++li)
#pragma unroll
    for (int ci = 0; ci < 4; ++ci)
#pragma unroll
      for (int j = 0; j < 4; ++j) {
        int row = rbase + li * 16 + lk * 4 + j;
        int d = ci * 16 + lr;
        ctx[((size_t)row * NB + n) * E_ + h * 64 + d] = f2bf(cacc[li][ci][j]);
      }
}

// ---------------- kernel 5: output projection ----------------
__global__ __launch_bounds__(256) void k_out(
    const short* __restrict__ ctxb, const short* __restrict__ wbf,
    const float* __restrict__ bias, float* __restrict__ out) {
  __shared__ short As[128 * LDT];
  __shared__ short Bs[128 * LDT];
  const int bm = blockIdx.x, bn = blockIdx.y;
  const int tid = threadIdx.x;
  const int lane = tid & 63, wid = tid >> 6;
  const int wr = wid >> 1, wc = wid & 1;
  const int lr = lane & 15, lk = lane >> 4;
  f32x4 acc[4][4] = {};
  for (int kb = 0; kb < E_; kb += 64) {
#pragma unroll
    for (int i = 0; i < 4; ++i) {
      int e8 = i * 256 + tid;
      int row = e8 >> 3, k8 = e8 & 7;
      int4 va = *(const int4*)&ctxb[(size_t)(bm * 128 + row) * E_ + kb + k8 * 8];
      *(int4*)&As[row * LDT + k8 * 8] = va;
      int4 vb = *(const int4*)&wbf[(size_t)(bn * 128 + row) * E_ + kb + k8 * 8];
      *(int4*)&Bs[row * LDT + k8 * 8] = vb;
    }
    __syncthreads();
#pragma unroll
    for (int kk = 0; kk < 2; ++kk) {
      bf16x8 a[4], b[4];
#pragma unroll
      for (int fi = 0; fi < 4; ++fi)
        a[fi] = *(const bf16x8*)&As[(wr * 64 + fi * 16 + lr) * LDT + kk * 32 + lk * 8];
#pragma unroll
      for (int ci = 0; ci < 4; ++ci)
        b[ci] = *(const bf16x8*)&Bs[(wc * 64 + ci * 16 + lr) * LDT + kk * 32 + lk * 8];
#pragma unroll
      for (int fi = 0; fi < 4; ++fi)
#pragma unroll
        for (int ci = 0; ci < 4; ++ci)
          acc[fi][ci] = __builtin_amdgcn_mfma_f32_16x16x32_bf16(a[fi], b[ci], acc[fi][ci], 0, 0, 0);
    }
    __syncthreads();
  }
#pragma unroll
  for (int ci = 0; ci < 4; ++ci) {
    int col = bn * 128 + wc * 64 + ci * 16 + lr;
    float b = bias[col];
#pragma unroll
    for (int fi = 0; fi < 4; ++fi)
#pragma unroll
      for (int j = 0; j < 4; ++j) {
        int m = bm * 128 + wr * 64 + fi * 16 + lk * 4 + j;
        out[(size_t)m * E_ + col] = acc[fi][ci][j] + b;
      }
  }
}

extern "C" void kernel_launch(void* const* d_in, const int* in_sizes, int n_in,
                              void* d_out, int out_size, void* d_ws, size_t ws_size,
                              hipStream_t stream) {
  const float* qin = (const float*)d_in[0];
  const float* kin = (const float*)d_in[1];
  const float* vin = (const float*)d_in[2];
  const float* wi  = (const float*)d_in[3];
  const float* bi  = (const float*)d_in[4];
  const float* wo  = (const float*)d_in[5];
  const float* bo  = (const float*)d_in[6];
  float* out = (float*)d_out;                       // (L,NB,E) fp32
  float* attnw = out + (size_t)L_ * NB * E_;        // (NB,L,S) fp32

  short* wqkv = (short*)d_ws;                       // 3E*E bf16
  short* wout = wqkv + (size_t)3 * E_ * E_;         // E*E bf16
  short* qh = wout + (size_t)E_ * E_;               // NB*H*L*D bf16 each
  short* kh = qh + (size_t)NB * L_ * E_;
  short* vh = kh + (size_t)NB * L_ * E_;
  short* vt = vh + (size_t)NB * L_ * E_;            // NB*H*(S/32)*D*32 bf16
  float* rl = (float*)(vt + (size_t)NB * L_ * E_);  // NB*H*L fp32
  short* ctx = (short*)(rl + (size_t)NB * H_ * L_); // L*NB*E bf16

  k_convert<<<1024, 256, 0, stream>>>(wi, wo, wqkv, wout);
  k_qkv<<<dim3(64, 24), 256, 0, stream>>>(qin, kin, vin, wqkv, bi, qh, kh, vh);
  k_vtrans<<<dim3(32, 64), 256, 0, stream>>>(vh, vt);
  k_stats<<<dim3(16, 64), 256, 0, stream>>>(qh, kh, rl);
  k_attn<<<256, 1024, 131072, stream>>>(qh, kh, vt, rl, attnw, ctx);
  k_out<<<dim3(64, 8), 256, 0, stream>>>(ctx, wout, bo, out);
}